// Round 2
// baseline (661.303 us; speedup 1.0000x reference)
//
#include <hip/hip_runtime.h>
#include <hip/hip_cooperative_groups.h>

namespace cg = cooperative_groups;

// Sparse 3D conv, gather formulation, R8: single cooperative kernel fusing
// prep + build_map + merge_feat + gather with grid-wide syncs. Theory: the
// 4-dispatch pipeline paid ~80 us of launch/drain/gap overhead (real work of
// the 3 small kernels is ~15 us); one dispatch pays it once.
//
// Phases (grid = 1728 x 256 = 442,368 threads, all co-resident):
//   P1: map[NSITE] = -1 (one int4/thread, exact fit) + pack W -> bf16 B-frags
//   P2: build_map: map[site] = vi via atomicExch, dup chain in nxt[vi]
//   P3: merge_feat: chain heads -> fp32-summed, bf16-packed rows (grid-stride)
//   P4: gather: wave owns 2 tiles of 16 outputs; map prefetch 1 offset ahead;
//       8 MFMA/offset into persistent C regs; coalesced stores (no memset).
// Fallback: if cooperative launch is rejected, run the 4 proven kernels.

#define DGRID 96
#define DOUT 48
#define CIN 32
#define COUT 64
#define NOFF 27
#define NSITE (2 * DGRID * DGRID * DGRID)     // 1,769,472 sites (B=2)
#define WPACK_ELEMS (NOFF * 4 * 64 * 8)       // 55,296 bf16
#define NTILE (2 * DOUT * DOUT * DOUT / 16)   // 13,824 tiles of 16 outputs
#define TPW 2                                 // tiles per wave
#define NWAVE (NTILE / TPW)                   // 6,912 waves
#define NBLK (NWAVE / 4)                      // 1,728 blocks (= NSITE/4/256)

typedef __attribute__((ext_vector_type(8))) short bf16x8;
typedef __attribute__((ext_vector_type(4))) float f32x4;

static __device__ __forceinline__ unsigned short f2bf_rne(float x) {
    unsigned u = __float_as_uint(x);
    u += 0x7fffu + ((u >> 16) & 1u);
    return (unsigned short)(u >> 16);
}

// Pack two fp32 -> bf16x2, round-half-up (same 2^-9 error bound as RNE).
static __device__ __forceinline__ unsigned pk_bf16(float lo, float hi) {
    unsigned a = __float_as_uint(lo) + 0x8000u;
    unsigned b = __float_as_uint(hi) + 0x8000u;
    return __builtin_amdgcn_perm(b, a, 0x07060302u);
}

// ---------------------------------------------------------------------------
// Shared phase bodies (used by both the fused kernel and the fallback path).
// ---------------------------------------------------------------------------

static __device__ __forceinline__ void wpack_one(
    const float* __restrict__ W, unsigned short* __restrict__ Wpack, int w)
{
    // Wpack[((o*4+f)*64+l)*8+j] = bf16(W[o][k][cout]),
    // k = (l>>4)*8 + j, cout = f*16 + (l&15).  (validated R4-R6)
    const int j = w & 7, l = (w >> 3) & 63, f = (w >> 9) & 3, o = w >> 11;
    const int k    = ((l >> 4) << 3) + j;
    const int cout = (f << 4) + (l & 15);
    Wpack[w] = f2bf_rne(W[(o * CIN + k) * COUT + cout]);
}

static __device__ __forceinline__ void build_one(
    const int* __restrict__ coors, int* __restrict__ map,
    int* __restrict__ nxt, int vi)
{
    const int b = coors[vi * 4 + 0];
    const int z = coors[vi * 4 + 1];
    const int y = coors[vi * 4 + 2];
    const int x = coors[vi * 4 + 3];
    const int site = ((b * DGRID + z) * DGRID + y) * DGRID + x;
    nxt[vi] = atomicExch(&map[site], vi);   // chain head swap (handles dups)
}

static __device__ __forceinline__ void merge_one(
    const float* __restrict__ feat, const int* __restrict__ coors,
    const int* __restrict__ map, const int* __restrict__ nxt,
    unsigned short* __restrict__ featbf, int tid)
{
    const int vi = tid >> 3, part = tid & 7;
    const int b = coors[vi * 4 + 0];
    const int z = coors[vi * 4 + 1];
    const int y = coors[vi * 4 + 2];
    const int x = coors[vi * 4 + 3];
    const int site = ((b * DGRID + z) * DGRID + y) * DGRID + x;
    if (map[site] != vi) return;          // not a chain head
    float4 s = *(const float4*)(feat + (size_t)vi * CIN + part * 4);
    int v2 = nxt[vi];
    while (v2 >= 0) {                     // ~3% of voxels; usually 0 iters
        const float4 u = *(const float4*)(feat + (size_t)v2 * CIN + part * 4);
        s.x += u.x; s.y += u.y; s.z += u.z; s.w += u.w;
        v2 = nxt[v2];
    }
    uint2 p;
    p.x = pk_bf16(s.x, s.y);
    p.y = pk_bf16(s.z, s.w);
    *(uint2*)(featbf + (size_t)vi * CIN + part * 4) = p;
}

// Gather phase body. wid in [0, NWAVE); lane = 64-lane id.
static __device__ __forceinline__ void gather_body(
    const unsigned short* __restrict__ featbf,
    const int*            __restrict__ map,
    const unsigned short* __restrict__ Wpack,
    float*                __restrict__ out,
    int wid, int lane)
{
    const int col   = lane & 15;      // output row within tile / C col
    const int khalf = lane >> 4;      // k-chunk for A-frag, row group for C

    // Decode this wave's tiles (wave-uniform -> SGPRs).
    int tb[TPW], tzo[TPW], tyo[TPW], txb[TPW];
#pragma unroll
    for (int t = 0; t < TPW; ++t) {
        const int tau = wid + t * NWAVE;
        const int x16 = tau % 3;
        const int r2  = tau / 3;
        tyo[t] = r2 % DOUT;
        const int r3 = r2 / DOUT;
        tzo[t] = r3 % DOUT;
        tb[t]  = r3 / DOUT;
        txb[t] = x16 << 4;
    }

    f32x4 acc[TPW][4];
#pragma unroll
    for (int t = 0; t < TPW; ++t)
#pragma unroll
        for (int q = 0; q < 4; ++q)
            acc[t][q] = (f32x4){0.f, 0.f, 0.f, 0.f};

    // Issue the map-row loads for kernel offset `off` (independent gathers).
    auto ldmap = [&](int off, int (&m)[TPW]) {
        const int kx = off % 3, ky = (off / 3) % 3, kz = off / 9;
#pragma unroll
        for (int t = 0; t < TPW; ++t) {
            const int zi = 2 * tzo[t] - 1 + kz;
            const int yi = 2 * tyo[t] - 1 + ky;
            int v = -1;
            if ((unsigned)zi < DGRID && (unsigned)yi < DGRID) {
                const int xi = 2 * (txb[t] + col) - 1 + kx;
                if ((unsigned)xi < DGRID)
                    v = map[((tb[t] * DGRID + zi) * DGRID + yi) * DGRID + xi];
            }
            m[t] = v;
        }
    };

    int mcur[TPW];
    ldmap(0, mcur);

    for (int off = 0; off < NOFF; ++off) {
        // B-frags for this offset (L1-hot after first wave).
        const bf16x8* wp = (const bf16x8*)Wpack + off * 256 + lane;
        const bf16x8 b0 = wp[0];
        const bf16x8 b1 = wp[64];
        const bf16x8 b2 = wp[128];
        const bf16x8 b3 = wp[192];

        // Pipeline: map loads for off+1 go in flight NOW, consumed next iter.
        int mnxt[TPW] = { -1, -1 };
        if (off + 1 < NOFF) ldmap(off + 1, mnxt);

        // Feat gathers for both tiles issue back-to-back (2 in flight).
        bf16x8 af[TPW];
        bool act[TPW];
#pragma unroll
        for (int t = 0; t < TPW; ++t) {
            act[t] = __ballot(mcur[t] >= 0) != 0ull;
            af[t] = (bf16x8)0;
            if (mcur[t] >= 0)
                af[t] = *(const bf16x8*)(featbf + (size_t)mcur[t] * CIN + (khalf << 3));
        }
#pragma unroll
        for (int t = 0; t < TPW; ++t) {
            if (!act[t]) continue;   // ~15% of rows entirely empty
            acc[t][0] = __builtin_amdgcn_mfma_f32_16x16x32_bf16(af[t], b0, acc[t][0], 0, 0, 0);
            acc[t][1] = __builtin_amdgcn_mfma_f32_16x16x32_bf16(af[t], b1, acc[t][1], 0, 0, 0);
            acc[t][2] = __builtin_amdgcn_mfma_f32_16x16x32_bf16(af[t], b2, acc[t][2], 0, 0, 0);
            acc[t][3] = __builtin_amdgcn_mfma_f32_16x16x32_bf16(af[t], b3, acc[t][3], 0, 0, 0);
        }
#pragma unroll
        for (int t = 0; t < TPW; ++t) mcur[t] = mnxt[t];
    }

    // Epilogue: plain coalesced stores; covers every output element once
    // (also provides the zeros -> no output memset anywhere).
    // C layout: col = lane&15, row = khalf*4 + r (HW-verified mapping).
#pragma unroll
    for (int t = 0; t < TPW; ++t) {
        const int tau = wid + t * NWAVE;
        float* ob = out + (size_t)tau * 16 * COUT;
#pragma unroll
        for (int r = 0; r < 4; ++r) {
            float* op = ob + ((khalf << 2) + r) * COUT + col;
            op[0]  = acc[t][0][r];
            op[16] = acc[t][1][r];
            op[32] = acc[t][2][r];
            op[48] = acc[t][3][r];
        }
    }
}

// ---------------------------------------------------------------------------
// Fused cooperative kernel.
// ---------------------------------------------------------------------------

__global__ __launch_bounds__(256, 7) void spconv_fused_kernel(
    const float* __restrict__ feat, const int* __restrict__ coors,
    const float* __restrict__ W, float* __restrict__ out,
    int* __restrict__ map, int* __restrict__ nxt,
    unsigned short* __restrict__ featbf, unsigned short* __restrict__ Wpack,
    int N)
{
    cg::grid_group grid = cg::this_grid();
    const int gtid = blockIdx.x * 256 + threadIdx.x;   // 0 .. 442,367

    // P1: map init (exactly one int4 per thread: NSITE/4 == NBLK*256) + Wpack.
    ((int4*)map)[gtid] = make_int4(-1, -1, -1, -1);
    if (gtid < WPACK_ELEMS) wpack_one(W, Wpack, gtid);
    grid.sync();

    // P2: build_map (N = 200k < 442k: single pass).
    if (gtid < N) build_one(coors, map, nxt, gtid);
    grid.sync();

    // P3: merge_feat, grid-stride over N*8 work items.
    for (int tid = gtid; tid < N * 8; tid += NBLK * 256)
        merge_one(feat, coors, map, nxt, featbf, tid);
    grid.sync();

    // P4: gather. wid = gtid>>6 covers [0, NWAVE) exactly.
    gather_body(featbf, map, Wpack, out, gtid >> 6, threadIdx.x & 63);
}

// ---------------------------------------------------------------------------
// Fallback kernels (proven R7 path) — used only if cooperative launch fails.
// ---------------------------------------------------------------------------

__global__ __launch_bounds__(256) void prep_kernel(
    const float* __restrict__ W, int* __restrict__ map,
    unsigned short* __restrict__ Wpack)
{
    const int tid = blockIdx.x * 256 + threadIdx.x;
    if (tid < NSITE / 4) {
        ((int4*)map)[tid] = make_int4(-1, -1, -1, -1);
        return;
    }
    const int w = tid - NSITE / 4;
    if (w < WPACK_ELEMS) wpack_one(W, Wpack, w);
}

__global__ __launch_bounds__(256) void build_map_kernel(
    const int* __restrict__ coors, int* __restrict__ map,
    int* __restrict__ nxt, int N)
{
    const int vi = blockIdx.x * 256 + threadIdx.x;
    if (vi >= N) return;
    build_one(coors, map, nxt, vi);
}

__global__ __launch_bounds__(256) void merge_feat_kernel(
    const float* __restrict__ feat, const int* __restrict__ coors,
    const int* __restrict__ map, const int* __restrict__ nxt,
    unsigned short* __restrict__ featbf, int N)
{
    const int tid = blockIdx.x * 256 + threadIdx.x;
    if (tid >= N * 8) return;
    merge_one(feat, coors, map, nxt, featbf, tid);
}

__global__ __launch_bounds__(256) void spconv_gather_kernel(
    const unsigned short* __restrict__ featbf,
    const int*            __restrict__ map,
    const unsigned short* __restrict__ Wpack,
    float*                __restrict__ out)
{
    const int wid = blockIdx.x * 4 + (threadIdx.x >> 6);
    gather_body(featbf, map, Wpack, out, wid, threadIdx.x & 63);
}

// ---------------------------------------------------------------------------

extern "C" void kernel_launch(void* const* d_in, const int* in_sizes, int n_in,
                              void* d_out, int out_size, void* d_ws, size_t ws_size,
                              hipStream_t stream) {
    const float* feat  = (const float*)d_in[0];
    const int*   coors = (const int*)d_in[1];
    const float* W     = (const float*)d_in[3];
    float*       out   = (float*)d_out;

    const int N = in_sizes[0] / CIN;  // 200000

    char* ws = (char*)d_ws;
    int* map = (int*)ws;                                        // 7,077,888 B
    int* nxt = (int*)(ws + (size_t)NSITE * 4);                  //   800,000 B
    const size_t featbf_off = (size_t)NSITE * 4 + (((size_t)N * 4 + 63) & ~(size_t)63);
    unsigned short* featbf = (unsigned short*)(ws + featbf_off);        // 12.8 MB
    const size_t wpack_off = featbf_off + (((size_t)N * CIN * 2 + 15) & ~(size_t)15);
    unsigned short* Wpack = (unsigned short*)(ws + wpack_off);          // 110,592 B
    // total ws use ~20.8 MB

    void* kargs[] = {
        (void*)&feat, (void*)&coors, (void*)&W, (void*)&out,
        (void*)&map, (void*)&nxt, (void*)&featbf, (void*)&Wpack, (void*)&N
    };
    hipError_t e = hipLaunchCooperativeKernel(
        (const void*)spconv_fused_kernel, dim3(NBLK), dim3(256), kargs, 0, stream);

    if (e != hipSuccess) {
        // Fallback: proven 4-kernel pipeline.
        const int prep_blocks = (NSITE / 4 + WPACK_ELEMS + 255) / 256;
        prep_kernel<<<prep_blocks, 256, 0, stream>>>(W, map, Wpack);
        build_map_kernel<<<(N + 255) / 256, 256, 0, stream>>>(coors, map, nxt, N);
        merge_feat_kernel<<<(N * 8 + 255) / 256, 256, 0, stream>>>(
            feat, coors, map, nxt, featbf, N);
        spconv_gather_kernel<<<NWAVE / 4, 256, 0, stream>>>(featbf, map, Wpack, out);
    }
}

// Round 3
// 155.044 us; speedup vs baseline: 4.2653x; 4.2653x over previous
//
#include <hip/hip_runtime.h>

// Sparse 3D conv, gather formulation, R9: revert R8 cooperative fusion
// (scratch-spilled accumulators, 590 us). Back to proven 4-kernel R7 path,
// with the gather's software pipeline deepened one stage:
//   map loads:  2 offsets ahead
//   feat loads: 1 offset ahead  (MFMA consumes rows issued a full iter ago)
// All pipeline state in named double-buffer vars (static indices only).
//
// prep:       map[B*96^3] = -1, pack W -> bf16 MFMA B-frags.
// build_map:  map[site] = vi via atomicExch; duplicate chain via nxt[vi].
// merge_feat: chain heads get fp32-summed, bf16-packed feature rows (64 B).
// gather:     wave owns 2 tiles of 16 output voxels; 8 MFMA/offset into
//             persistent C regs; plain coalesced stores (no memset).

#define DGRID 96
#define DOUT 48
#define CIN 32
#define COUT 64
#define NOFF 27
#define NSITE (2 * DGRID * DGRID * DGRID)     // 1,769,472 sites (B=2)
#define WPACK_ELEMS (NOFF * 4 * 64 * 8)       // 55,296 bf16
#define NTILE (2 * DOUT * DOUT * DOUT / 16)   // 13,824 tiles of 16 outputs
#define TPW 2                                 // tiles per wave
#define NWAVE (NTILE / TPW)                   // 6,912 waves -> 1,728 blocks

typedef __attribute__((ext_vector_type(8))) short bf16x8;
typedef __attribute__((ext_vector_type(4))) float f32x4;

static __device__ __forceinline__ unsigned short f2bf_rne(float x) {
    unsigned u = __float_as_uint(x);
    u += 0x7fffu + ((u >> 16) & 1u);
    return (unsigned short)(u >> 16);
}

// Pack two fp32 -> bf16x2, round-half-up (same 2^-9 error bound as RNE).
static __device__ __forceinline__ unsigned pk_bf16(float lo, float hi) {
    unsigned a = __float_as_uint(lo) + 0x8000u;
    unsigned b = __float_as_uint(hi) + 0x8000u;
    return __builtin_amdgcn_perm(b, a, 0x07060302u);
}

// ws layout: int map[NSITE] | int nxt[N] (64B-pad) | bf16 featbf[N*CIN] | bf16 Wpack

__global__ __launch_bounds__(256) void prep_kernel(
    const float* __restrict__ W, int* __restrict__ map,
    unsigned short* __restrict__ Wpack)
{
    const int tid = blockIdx.x * 256 + threadIdx.x;
    if (tid < NSITE / 4) {
        ((int4*)map)[tid] = make_int4(-1, -1, -1, -1);
        return;
    }
    const int w = tid - NSITE / 4;
    if (w < WPACK_ELEMS) {
        // Wpack[((o*4+f)*64+l)*8+j] = bf16(W[o][k][cout]),
        // k = (l>>4)*8 + j, cout = f*16 + (l&15).  (validated R4-R6)
        const int j = w & 7, l = (w >> 3) & 63, f = (w >> 9) & 3, o = w >> 11;
        const int k    = ((l >> 4) << 3) + j;
        const int cout = (f << 4) + (l & 15);
        Wpack[w] = f2bf_rne(W[(o * CIN + k) * COUT + cout]);
    }
}

__global__ __launch_bounds__(256) void build_map_kernel(
    const int* __restrict__ coors, int* __restrict__ map,
    int* __restrict__ nxt, int N)
{
    const int vi = blockIdx.x * 256 + threadIdx.x;
    if (vi >= N) return;
    const int b = coors[vi * 4 + 0];
    const int z = coors[vi * 4 + 1];
    const int y = coors[vi * 4 + 2];
    const int x = coors[vi * 4 + 3];
    const int site = ((b * DGRID + z) * DGRID + y) * DGRID + x;
    nxt[vi] = atomicExch(&map[site], vi);   // chain head swap (handles dups)
}

// 8 threads per voxel (part = 4 channels each). Chain heads sum duplicate
// rows in fp32 and store a 64 B bf16 row; non-heads are never read.
__global__ __launch_bounds__(256) void merge_feat_kernel(
    const float* __restrict__ feat, const int* __restrict__ coors,
    const int* __restrict__ map, const int* __restrict__ nxt,
    unsigned short* __restrict__ featbf, int N)
{
    const int tid = blockIdx.x * 256 + threadIdx.x;
    const int vi = tid >> 3, part = tid & 7;
    if (vi >= N) return;
    const int b = coors[vi * 4 + 0];
    const int z = coors[vi * 4 + 1];
    const int y = coors[vi * 4 + 2];
    const int x = coors[vi * 4 + 3];
    const int site = ((b * DGRID + z) * DGRID + y) * DGRID + x;
    if (map[site] != vi) return;          // not a chain head
    float4 s = *(const float4*)(feat + (size_t)vi * CIN + part * 4);
    int v2 = nxt[vi];
    while (v2 >= 0) {                     // ~3% of voxels; usually 0 iters
        const float4 u = *(const float4*)(feat + (size_t)v2 * CIN + part * 4);
        s.x += u.x; s.y += u.y; s.z += u.z; s.w += u.w;
        v2 = nxt[v2];
    }
    uint2 p;
    p.x = pk_bf16(s.x, s.y);
    p.y = pk_bf16(s.z, s.w);
    *(uint2*)(featbf + (size_t)vi * CIN + part * 4) = p;
}

__global__ __launch_bounds__(256) void spconv_gather_kernel(
    const unsigned short* __restrict__ featbf,  // [N, CIN] bf16, chain-merged
    const int*            __restrict__ map,     // [NSITE] head voxel or -1
    const unsigned short* __restrict__ Wpack,   // bf16 B-frag layout
    float*                __restrict__ out)     // [B*DOUT^3, COUT]
{
    const int lane  = threadIdx.x & 63;
    const int col   = lane & 15;      // output row within tile / C col
    const int khalf = lane >> 4;      // k-chunk for A-frag, row group for C
    const int wid   = blockIdx.x * 4 + (threadIdx.x >> 6);   // 0..NWAVE-1

    // Decode this wave's tiles (wave-uniform -> SGPRs).
    int tb[TPW], tzo[TPW], tyo[TPW], txb[TPW];
#pragma unroll
    for (int t = 0; t < TPW; ++t) {
        const int tau = wid + t * NWAVE;
        const int x16 = tau % 3;
        const int r2  = tau / 3;
        tyo[t] = r2 % DOUT;
        const int r3 = r2 / DOUT;
        tzo[t] = r3 % DOUT;
        tb[t]  = r3 / DOUT;
        txb[t] = x16 << 4;
    }

    f32x4 acc[TPW][4];
#pragma unroll
    for (int t = 0; t < TPW; ++t)
#pragma unroll
        for (int q = 0; q < 4; ++q)
            acc[t][q] = (f32x4){0.f, 0.f, 0.f, 0.f};

    // Issue the map-row loads for kernel offset `off` (independent gathers).
    auto ldmap = [&](int off, int (&m)[TPW]) {
        const int kx = off % 3, ky = (off / 3) % 3, kz = off / 9;
#pragma unroll
        for (int t = 0; t < TPW; ++t) {
            const int zi = 2 * tzo[t] - 1 + kz;
            const int yi = 2 * tyo[t] - 1 + ky;
            int v = -1;
            if ((unsigned)zi < DGRID && (unsigned)yi < DGRID) {
                const int xi = 2 * (txb[t] + col) - 1 + kx;
                if ((unsigned)xi < DGRID)
                    v = map[((tb[t] * DGRID + zi) * DGRID + yi) * DGRID + xi];
            }
            m[t] = v;
        }
    };

    // Feature-row gathers + active mask for one offset's map values.
    auto ldfeat = [&](const int (&m)[TPW], bf16x8 (&af)[TPW], bool (&act)[TPW]) {
#pragma unroll
        for (int t = 0; t < TPW; ++t) {
            act[t] = __ballot(m[t] >= 0) != 0ull;
            af[t] = (bf16x8)0;
            if (m[t] >= 0)
                af[t] = *(const bf16x8*)(featbf + (size_t)m[t] * CIN + (khalf << 3));
        }
    };

    // Pipeline prologue: map for off=0 and off=1 in flight, feat for off=0.
    int m0[TPW], m_nxt[TPW];
    ldmap(0, m0);
    ldmap(1, m_nxt);
    bf16x8 af_cur[TPW];
    bool   act_cur[TPW];
    ldfeat(m0, af_cur, act_cur);   // waits only on ldmap(0); ldmap(1) stays in flight

    for (int off = 0; off < NOFF; ++off) {
        // B-frags for this offset (L1-hot after first wave).
        const bf16x8* wp = (const bf16x8*)Wpack + off * 256 + lane;
        const bf16x8 b0 = wp[0];
        const bf16x8 b1 = wp[64];
        const bf16x8 b2 = wp[128];
        const bf16x8 b3 = wp[192];

        // Map loads for off+2 go in flight now.
        int m_nn[TPW] = { -1, -1 };
        if (off + 2 < NOFF) ldmap(off + 2, m_nn);

        // Feat gathers for off+1 go in flight now (map row arrived ~1 iter ago).
        bf16x8 af_nxt[TPW];
        bool   act_nxt[TPW];
#pragma unroll
        for (int t = 0; t < TPW; ++t) { af_nxt[t] = (bf16x8)0; act_nxt[t] = false; }
        if (off + 1 < NOFF) ldfeat(m_nxt, af_nxt, act_nxt);

        // MFMA consumes feat rows issued a full iteration ago; the waitcnt
        // here leaves this iteration's map+feat loads in flight.
#pragma unroll
        for (int t = 0; t < TPW; ++t) {
            if (!act_cur[t]) continue;   // ~15% of rows entirely empty
            acc[t][0] = __builtin_amdgcn_mfma_f32_16x16x32_bf16(af_cur[t], b0, acc[t][0], 0, 0, 0);
            acc[t][1] = __builtin_amdgcn_mfma_f32_16x16x32_bf16(af_cur[t], b1, acc[t][1], 0, 0, 0);
            acc[t][2] = __builtin_amdgcn_mfma_f32_16x16x32_bf16(af_cur[t], b2, acc[t][2], 0, 0, 0);
            acc[t][3] = __builtin_amdgcn_mfma_f32_16x16x32_bf16(af_cur[t], b3, acc[t][3], 0, 0, 0);
        }

        // Rotate pipeline state (static indices only -> stays in registers).
#pragma unroll
        for (int t = 0; t < TPW; ++t) {
            m_nxt[t]   = m_nn[t];
            af_cur[t]  = af_nxt[t];
            act_cur[t] = act_nxt[t];
        }
    }

    // Epilogue: plain coalesced stores; covers every output element once
    // (also provides the zeros -> no output memset anywhere).
    // C layout: col = lane&15, row = khalf*4 + r (HW-verified mapping).
#pragma unroll
    for (int t = 0; t < TPW; ++t) {
        const int tau = wid + t * NWAVE;
        float* ob = out + (size_t)tau * 16 * COUT;
#pragma unroll
        for (int r = 0; r < 4; ++r) {
            float* op = ob + ((khalf << 2) + r) * COUT + col;
            op[0]  = acc[t][0][r];
            op[16] = acc[t][1][r];
            op[32] = acc[t][2][r];
            op[48] = acc[t][3][r];
        }
    }
}

extern "C" void kernel_launch(void* const* d_in, const int* in_sizes, int n_in,
                              void* d_out, int out_size, void* d_ws, size_t ws_size,
                              hipStream_t stream) {
    const float* feat  = (const float*)d_in[0];
    const int*   coors = (const int*)d_in[1];
    const float* W     = (const float*)d_in[3];
    float*       out   = (float*)d_out;

    const int N = in_sizes[0] / CIN;  // 200000

    char* ws = (char*)d_ws;
    int* map = (int*)ws;                                        // 7,077,888 B
    int* nxt = (int*)(ws + (size_t)NSITE * 4);                  //   800,000 B
    const size_t featbf_off = (size_t)NSITE * 4 + (((size_t)N * 4 + 63) & ~(size_t)63);
    unsigned short* featbf = (unsigned short*)(ws + featbf_off);        // 12.8 MB
    const size_t wpack_off = featbf_off + (((size_t)N * CIN * 2 + 15) & ~(size_t)15);
    unsigned short* Wpack = (unsigned short*)(ws + wpack_off);          // 110,592 B
    // total ws use ~20.8 MB

    const int prep_blocks = (NSITE / 4 + WPACK_ELEMS + 255) / 256;
    prep_kernel<<<prep_blocks, 256, 0, stream>>>(W, map, Wpack);

    build_map_kernel<<<(N + 255) / 256, 256, 0, stream>>>(coors, map, nxt, N);

    merge_feat_kernel<<<(N * 8 + 255) / 256, 256, 0, stream>>>(
        feat, coors, map, nxt, featbf, N);

    spconv_gather_kernel<<<NWAVE / 4, 256, 0, stream>>>(featbf, map, Wpack, out);
}